// Round 2
// baseline (230.518 us; speedup 1.0000x reference)
//
#include <hip/hip_runtime.h>

// KeyValueMemoryNetwork: B=16, S=2048, C=16, D=256, V=100000
// R6b: single-phase gather — all 16 table rows issued back-to-back before any
// consumption, single-pass softmax (no online rescale). Doubles per-wave
// memory-level parallelism (16 KB in flight vs 8 KB) and removes the
// serialized {compute -> second load phase} latency exposure of the
// 2-chunk online-softmax version. e[16] = 64 VGPRs stays within the
// 128-VGPR / 4-waves-per-EU budget.
// Streaming hidden/out use nontemporal hints (via native clang vector type —
// HIP_vector_type is rejected by the builtin) to avoid evicting table rows
// from L2 (table is the only data with reuse).

#define KV_C 16
#define KV_D 256
#define KV_TOKENS (16 * 2048)

typedef float vfloat4 __attribute__((ext_vector_type(4)));

__global__ __launch_bounds__(256, 4) void kv_mem_kernel(
    const int* __restrict__ seq,      // [TOKENS, C] int32
    const float* __restrict__ hidden, // [TOKENS, D]
    const float* __restrict__ table,  // [V, D]
    float* __restrict__ out)          // [TOKENS, D]
{
    const int wave = threadIdx.x >> 6;
    const int lane = threadIdx.x & 63;
    const int token = blockIdx.x * 4 + wave;

    // hidden chunk for this lane (streaming: read once, keep out of L2)
    const vfloat4 h = __builtin_nontemporal_load(
        (const vfloat4*)(hidden + (size_t)token * KV_D + lane * 4));

    // lanes 0..15 hold the 16 indices; broadcast via shuffle
    const int* sp = seq + (size_t)token * KV_C;
    int myidx = (lane < KV_C) ? sp[lane] : 0;
    const unsigned long long nz = __ballot(myidx != 0);

    // Phase A: ALL 16 gathers issued back-to-back, nothing waits yet.
    // (row 0 is valid memory; padding handled by mask below)
    float4 e[KV_C];
    #pragma unroll
    for (int j = 0; j < KV_C; ++j) {
        const int idx = __shfl(myidx, j);   // wave-uniform
        e[j] = *(const float4*)(table + (size_t)idx * KV_D + lane * 4);
    }

    // Phase B: partial dots, consumed in load order so the compiler can use
    // progressive vmcnt and overlap early dots with late loads in flight.
    // Masked -> padded slots give u == 0 exactly, matching the reference
    // (which softmaxes over zeroed rows too).
    float u[KV_C];
    #pragma unroll
    for (int j = 0; j < KV_C; ++j) {
        const float msk = ((nz >> j) & 1ULL) ? 1.0f : 0.0f;
        u[j] = msk * (h.x * e[j].x + h.y * e[j].y +
                      h.z * e[j].z + h.w * e[j].w);
    }

    // butterfly-reduce the 16 scores across the 64-lane wave
    #pragma unroll
    for (int s = 32; s >= 1; s >>= 1) {
        #pragma unroll
        for (int j = 0; j < KV_C; ++j) {
            u[j] += __shfl_xor(u[j], s);
        }
    }

    // Phase C: single-pass softmax (all scores known -> no online rescale).
    float m = u[0];
    #pragma unroll
    for (int j = 1; j < KV_C; ++j) m = fmaxf(m, u[j]);

    float Z = 0.0f;
    #pragma unroll
    for (int j = 0; j < KV_C; ++j) {
        u[j] = __expf(u[j] - m);   // reuse u[] as the unnormalized weights
        Z += u[j];                 // Z includes padded slots (exp(0-m)), as in ref
    }

    // Phase D: weighted combine; mask zeroes the padded rows' vectors.
    float4 o = make_float4(0.f, 0.f, 0.f, 0.f);
    #pragma unroll
    for (int j = 0; j < KV_C; ++j) {
        const float msk = ((nz >> j) & 1ULL) ? 1.0f : 0.0f;
        const float wm = u[j] * msk;
        o.x += wm * e[j].x;
        o.y += wm * e[j].y;
        o.z += wm * e[j].z;
        o.w += wm * e[j].w;
    }

    const float inv = 1.0f / Z;
    vfloat4 ov;
    ov.x = o.x * inv; ov.y = o.y * inv; ov.z = o.z * inv; ov.w = o.w * inv;

    __builtin_nontemporal_store(ov,
        (vfloat4*)(out + (size_t)token * KV_D + lane * 4));
}

extern "C" void kernel_launch(void* const* d_in, const int* in_sizes, int n_in,
                              void* d_out, int out_size, void* d_ws, size_t ws_size,
                              hipStream_t stream) {
    const int*   seq    = (const int*)d_in[0];
    const float* hidden = (const float*)d_in[1];
    const float* table  = (const float*)d_in[2];
    float*       out    = (float*)d_out;

    dim3 grid(KV_TOKENS / 4);   // 8192 blocks, 4 waves (tokens) per block
    dim3 block(256);
    kv_mem_kernel<<<grid, block, 0, stream>>>(seq, hidden, table, out);
}

// Round 3
// 229.909 us; speedup vs baseline: 1.0027x; 1.0027x over previous
//
#include <hip/hip_runtime.h>

// KeyValueMemoryNetwork: B=16, S=2048, C=16, D=256, V=100000
// R7: decisive MLP test. R6b asked for 16 gathers in flight but the compiler
// sank the loads into the consume loop to save registers (VGPR_Count=56
// proves it — 16 live float4 rows alone need 64 VGPRs), so only ~5 loads
// were ever outstanding. This version pins the schedule with
// sched_barrier(0): all 16 table-row loads are issued before ANY consumer,
// forcing e[0..15] live (~105 VGPR, still >=4 waves/EU at the 128-reg
// budget).
//   - If the kernel is MLP/latency-limited: BW 3.2 -> ~4.3+ TB/s.
//   - If the L2-miss path is saturated: no change, and that (4 structures,
//     2 occupancies, 2 true MLP depths, same 3.2 TB/s) is the roofline
//     evidence.

#define KV_C 16
#define KV_D 256
#define KV_TOKENS (16 * 2048)

typedef float vfloat4 __attribute__((ext_vector_type(4)));

__global__ __launch_bounds__(256, 4) void kv_mem_kernel(
    const int* __restrict__ seq,      // [TOKENS, C] int32
    const float* __restrict__ hidden, // [TOKENS, D]
    const float* __restrict__ table,  // [V, D]
    float* __restrict__ out)          // [TOKENS, D]
{
    const int wave = threadIdx.x >> 6;
    const int lane = threadIdx.x & 63;
    const int token = blockIdx.x * 4 + wave;

    // hidden chunk for this lane (streaming: read once, keep out of L2)
    const vfloat4 h = __builtin_nontemporal_load(
        (const vfloat4*)(hidden + (size_t)token * KV_D + lane * 4));

    // lanes 0..15 hold the 16 indices; broadcast via shuffle
    const int* sp = seq + (size_t)token * KV_C;
    int myidx = (lane < KV_C) ? sp[lane] : 0;
    const unsigned long long nz = __ballot(myidx != 0);

    // Phase A: ALL 16 gathers issued back-to-back. The sched_barrier(0)
    // fence below forbids the scheduler from sinking any of these loads
    // past it (or hoisting consumers above it), so all 16 rows are
    // genuinely in flight simultaneously (16 KB/wave of MLP).
    float4 e[KV_C];
    #pragma unroll
    for (int j = 0; j < KV_C; ++j) {
        const int idx = __shfl(myidx, j);   // wave-uniform
        e[j] = *(const float4*)(table + (size_t)idx * KV_D + lane * 4);
    }
    __builtin_amdgcn_sched_barrier(0);

    // Phase B: partial dots, consumed in load order (progressive vmcnt:
    // the dot of row j waits only for load j, overlapping with the tail
    // loads still in flight). Masked -> padded slots give u == 0 exactly,
    // matching the reference (which softmaxes over zeroed rows too).
    float u[KV_C];
    #pragma unroll
    for (int j = 0; j < KV_C; ++j) {
        const float msk = ((nz >> j) & 1ULL) ? 1.0f : 0.0f;
        u[j] = msk * (h.x * e[j].x + h.y * e[j].y +
                      h.z * e[j].z + h.w * e[j].w);
    }

    // butterfly-reduce the 16 scores across the 64-lane wave
    #pragma unroll
    for (int s = 32; s >= 1; s >>= 1) {
        #pragma unroll
        for (int j = 0; j < KV_C; ++j) {
            u[j] += __shfl_xor(u[j], s);
        }
    }

    // Phase C: single-pass softmax (all scores known -> no online rescale).
    float m = u[0];
    #pragma unroll
    for (int j = 1; j < KV_C; ++j) m = fmaxf(m, u[j]);

    float Z = 0.0f;
    #pragma unroll
    for (int j = 0; j < KV_C; ++j) {
        u[j] = __expf(u[j] - m);   // reuse u[] as the unnormalized weights
        Z += u[j];                 // Z includes padded slots (exp(0-m)), as in ref
    }

    // Phase D: weighted combine; mask zeroes the padded rows' vectors.
    float4 o = make_float4(0.f, 0.f, 0.f, 0.f);
    #pragma unroll
    for (int j = 0; j < KV_C; ++j) {
        const float msk = ((nz >> j) & 1ULL) ? 1.0f : 0.0f;
        const float wm = u[j] * msk;
        o.x += wm * e[j].x;
        o.y += wm * e[j].y;
        o.z += wm * e[j].z;
        o.w += wm * e[j].w;
    }

    const float inv = 1.0f / Z;
    vfloat4 ov;
    ov.x = o.x * inv; ov.y = o.y * inv; ov.z = o.z * inv; ov.w = o.w * inv;

    __builtin_nontemporal_store(ov,
        (vfloat4*)(out + (size_t)token * KV_D + lane * 4));
}

extern "C" void kernel_launch(void* const* d_in, const int* in_sizes, int n_in,
                              void* d_out, int out_size, void* d_ws, size_t ws_size,
                              hipStream_t stream) {
    const int*   seq    = (const int*)d_in[0];
    const float* hidden = (const float*)d_in[1];
    const float* table  = (const float*)d_in[2];
    float*       out    = (float*)d_out;

    dim3 grid(KV_TOKENS / 4);   // 8192 blocks, 4 waves (tokens) per block
    dim3 block(256);
    kv_mem_kernel<<<grid, block, 0, stream>>>(seq, hidden, table, out);
}